// Round 1
// baseline (2112.515 us; speedup 1.0000x reference)
//
#include <hip/hip_runtime.h>
#include <math.h>

// ---------------------------------------------------------------------------
// NN_35562329211597: q = trunk(x), k = trunk(x_n) with trunk = 3x [BN -> Linear -> tanh]
// out[i] = clip( softmax_j(2 q_i.k_j - ||k_j||^2) @ y_n , 0, 1 )
// (the -||q_i||^2 row-constant cancels inside softmax)
//
// fp32 baseline. BN folded into GEMM: BN(x) = s*x + t  =>  layer = tanh(x @ (s∘W) + b + t@W).
// s applied while staging W tiles into LDS; t@W accumulated by a small fold kernel.
// ---------------------------------------------------------------------------

__device__ __forceinline__ float fast_tanh(float x) {
    // overflow-safe: uses exp(-2|x|) in [0,1]
    float ax = fabsf(x);
    float e  = __expf(-2.0f * ax);
    float r  = (1.0f - e) / (1.0f + e);
    return copysignf(r, x);
}

// -------- per-column mean/meansq partial sums (atomics into zeroed ws) -----
__global__ void col_stats(const float* __restrict__ X, float* __restrict__ csum,
                          float* __restrict__ csumsq, int R, int C, int rows_per_block) {
    int c  = blockIdx.x * blockDim.x + threadIdx.x;
    int r0 = blockIdx.y * rows_per_block;
    int r1 = r0 + rows_per_block; if (r1 > R) r1 = R;
    float s = 0.f, q = 0.f;
    for (int r = r0; r < r1; ++r) {
        float v = X[(size_t)r * C + c];
        s += v; q += v * v;
    }
    atomicAdd(&csum[c], s);
    atomicAdd(&csumsq[c], q);
}

// -------- BN affine fold: s = g*rsqrt(var+eps), t = beta - mean*s ----------
__global__ void bn_prep(const float* __restrict__ csum, const float* __restrict__ csumsq,
                        const float* __restrict__ g, const float* __restrict__ beta,
                        float* __restrict__ s_out, float* __restrict__ t_out,
                        int C, float invR) {
    int c = blockIdx.x * blockDim.x + threadIdx.x;
    if (c >= C) return;
    float mean = csum[c] * invR;
    float var  = fmaxf(csumsq[c] * invR - mean * mean, 0.f);
    float s    = g[c] * rsqrtf(var + 1e-5f);
    s_out[c] = s;
    t_out[c] = beta[c] - mean * s;
}

// -------- bias correction: bacc[f] += sum_c t[c] * W[c][f] -----------------
__global__ void fold_bias(const float* __restrict__ W, const float* __restrict__ t_,
                          float* __restrict__ bacc, int C, int F, int cch) {
    int f  = blockIdx.x * blockDim.x + threadIdx.x;
    int c0 = blockIdx.y * cch;
    float acc = 0.f;
    for (int c = c0; c < c0 + cch; ++c)
        acc += t_[c] * W[(size_t)c * F + f];
    atomicAdd(&bacc[f], acc);
}

// -------- fused GEMM: Y = tanh( X @ (s∘W) + b + bacc ), optional transposed store
template <bool TRANS_STORE>
__global__ __launch_bounds__(256) void gemm_bn_tanh(
        const float* __restrict__ X, const float* __restrict__ W,
        const float* __restrict__ s_, const float* __restrict__ bias,
        const float* __restrict__ bacc, float* __restrict__ Y,
        int R, int C, int F) {
    __shared__ float As[16][68];   // A chunk, transposed: As[k][i]
    __shared__ float Bs[16][68];   // B chunk: Bs[k][f]
    const int tid = threadIdx.x;
    const int tx = tid & 15, ty = tid >> 4;
    const int i0 = blockIdx.x * 64, f0 = blockIdx.y * 64;
    const int ai = tid >> 2, ak = (tid & 3) * 4;   // A load: 64 rows x 16 k
    const int bk = tid >> 4, bf = (tid & 15) * 4;  // B load: 16 k x 64 f
    float acc[4][4] = {};
    for (int k0 = 0; k0 < C; k0 += 16) {
        float4 av = *(const float4*)&X[(size_t)(i0 + ai) * C + k0 + ak];
        float  sc = s_[k0 + bk];
        float4 bv = *(const float4*)&W[(size_t)(k0 + bk) * F + f0 + bf];
        As[ak + 0][ai] = av.x; As[ak + 1][ai] = av.y;
        As[ak + 2][ai] = av.z; As[ak + 3][ai] = av.w;
        bv.x *= sc; bv.y *= sc; bv.z *= sc; bv.w *= sc;
        *(float4*)&Bs[bk][bf] = bv;
        __syncthreads();
#pragma unroll
        for (int kc = 0; kc < 16; ++kc) {
            float4 a4 = *(const float4*)&As[kc][ty * 4];
            float4 b4 = *(const float4*)&Bs[kc][tx * 4];
            float a[4] = {a4.x, a4.y, a4.z, a4.w};
            float b[4] = {b4.x, b4.y, b4.z, b4.w};
#pragma unroll
            for (int ia = 0; ia < 4; ++ia)
#pragma unroll
                for (int ib = 0; ib < 4; ++ib)
                    acc[ia][ib] += a[ia] * b[ib];
        }
        __syncthreads();
    }
#pragma unroll
    for (int ia = 0; ia < 4; ++ia) {
        int i = i0 + ty * 4 + ia;
#pragma unroll
        for (int ib = 0; ib < 4; ++ib) {
            int f = f0 + tx * 4 + ib;
            float v = fast_tanh(acc[ia][ib] + bias[f] + bacc[f]);
            if (TRANS_STORE) Y[(size_t)f * R + i] = v;   // K^T layout [F][R]
            else             Y[(size_t)i * F + f] = v;
        }
    }
}

// -------- ||k_j||^2 from transposed K ---------------------------------------
__global__ void k2norm_k(const float* __restrict__ KT, float* __restrict__ k2n, int NJ) {
    int j = blockIdx.x * blockDim.x + threadIdx.x;
    float acc = 0.f;
    for (int d = 0; d < 256; ++d) {
        float v = KT[(size_t)d * NJ + j];
        acc += v * v;
    }
    k2n[j] = acc;
}

// -------- flash attention over j with V = y_n (scalar per j) ---------------
// logits = 2 Q.K^T - k2 ; online softmax, j-split partials (m, l, o)
__global__ __launch_bounds__(256) void flash_attn(
        const float* __restrict__ Q, const float* __restrict__ KT,
        const float* __restrict__ k2n, const float* __restrict__ yv,
        float* __restrict__ pm, float* __restrict__ pl, float* __restrict__ po,
        int NJ, int jlen, int nsplit) {
    __shared__ float Qs[16][68];   // Qs[d][i]
    __shared__ float Ks[16][68];   // Ks[d][j]
    const int tid = threadIdx.x;
    const int tx = tid & 15, ty = tid >> 4;
    const int i0 = blockIdx.x * 64;
    const int jb = blockIdx.y * jlen;
    const int qi = tid >> 2, qk = (tid & 3) * 4;   // Q chunk load: 64 rows x 16 d
    const int kd = tid >> 4, kj = (tid & 15) * 4;  // K chunk load: 16 d x 64 j

    float mrun[4], lrun[4], orun[4];
#pragma unroll
    for (int a = 0; a < 4; ++a) { mrun[a] = -INFINITY; lrun[a] = 0.f; orun[a] = 0.f; }

    for (int j0 = jb; j0 < jb + jlen; j0 += 64) {
        float acc[4][4] = {};
        for (int d0 = 0; d0 < 256; d0 += 16) {
            float4 qv = *(const float4*)&Q[(size_t)(i0 + qi) * 256 + d0 + qk];
            float4 kv = *(const float4*)&KT[(size_t)(d0 + kd) * NJ + j0 + kj];
            Qs[qk + 0][qi] = qv.x; Qs[qk + 1][qi] = qv.y;
            Qs[qk + 2][qi] = qv.z; Qs[qk + 3][qi] = qv.w;
            *(float4*)&Ks[kd][kj] = kv;
            __syncthreads();
#pragma unroll
            for (int dc = 0; dc < 16; ++dc) {
                float4 q4 = *(const float4*)&Qs[dc][ty * 4];
                float4 k4 = *(const float4*)&Ks[dc][tx * 4];
                float a[4] = {q4.x, q4.y, q4.z, q4.w};
                float b[4] = {k4.x, k4.y, k4.z, k4.w};
#pragma unroll
                for (int ia = 0; ia < 4; ++ia)
#pragma unroll
                    for (int ib = 0; ib < 4; ++ib)
                        acc[ia][ib] += a[ia] * b[ib];
            }
            __syncthreads();
        }
        float4 k2f = *(const float4*)&k2n[j0 + tx * 4];
        float4 yf  = *(const float4*)&yv[j0 + tx * 4];
        float k2a[4] = {k2f.x, k2f.y, k2f.z, k2f.w};
        float ya[4]  = {yf.x, yf.y, yf.z, yf.w};
#pragma unroll
        for (int a = 0; a < 4; ++a) {
            float lg[4], mt = -INFINITY;
#pragma unroll
            for (int b = 0; b < 4; ++b) {
                lg[b] = 2.f * acc[a][b] - k2a[b];
                mt = fmaxf(mt, lg[b]);
            }
#pragma unroll
            for (int m = 1; m < 16; m <<= 1) mt = fmaxf(mt, __shfl_xor(mt, m));
            float mnew = fmaxf(mrun[a], mt);
            float sp = 0.f, spy = 0.f;
#pragma unroll
            for (int b = 0; b < 4; ++b) {
                float p = __expf(lg[b] - mnew);
                sp  += p;
                spy += p * ya[b];
            }
#pragma unroll
            for (int m = 1; m < 16; m <<= 1) {
                sp  += __shfl_xor(sp, m);
                spy += __shfl_xor(spy, m);
            }
            float scale = __expf(mrun[a] - mnew);  // exp(-inf)=0 on first tile
            lrun[a] = lrun[a] * scale + sp;
            orun[a] = orun[a] * scale + spy;
            mrun[a] = mnew;
        }
    }
    if (tx == 0) {
#pragma unroll
        for (int a = 0; a < 4; ++a) {
            int row = i0 + ty * 4 + a;
            pm[(size_t)row * nsplit + blockIdx.y] = mrun[a];
            pl[(size_t)row * nsplit + blockIdx.y] = lrun[a];
            po[(size_t)row * nsplit + blockIdx.y] = orun[a];
        }
    }
}

// -------- combine j-split partials -----------------------------------------
__global__ void combine_k(const float* __restrict__ pm, const float* __restrict__ pl,
                          const float* __restrict__ po, float* __restrict__ out,
                          int B, int nsplit) {
    int i = blockIdx.x * blockDim.x + threadIdx.x;
    if (i >= B) return;
    float M = -INFINITY;
    for (int s = 0; s < nsplit; ++s) M = fmaxf(M, pm[(size_t)i * nsplit + s]);
    float L = 0.f, O = 0.f;
    for (int s = 0; s < nsplit; ++s) {
        float w = __expf(pm[(size_t)i * nsplit + s] - M);
        L += pl[(size_t)i * nsplit + s] * w;
        O += po[(size_t)i * nsplit + s] * w;
    }
    float r = O / L;
    out[i] = fminf(fmaxf(r, 0.f), 1.f);
}

// ---------------------------------------------------------------------------
extern "C" void kernel_launch(void* const* d_in, const int* in_sizes, int n_in,
                              void* d_out, int out_size, void* d_ws, size_t ws_size,
                              hipStream_t stream) {
    const float* x   = (const float*)d_in[0];   // [4096,1024]
    const float* x_n = (const float*)d_in[1];   // [8192,1024]
    const float* y_n = (const float*)d_in[2];   // [8192,1]
    const float* Wm[3]   = {(const float*)d_in[3],  (const float*)d_in[7],  (const float*)d_in[11]};
    const float* bm[3]   = {(const float*)d_in[4],  (const float*)d_in[8],  (const float*)d_in[12]};
    const float* gm[3]   = {(const float*)d_in[5],  (const float*)d_in[9],  (const float*)d_in[13]};
    const float* betam[3]= {(const float*)d_in[6],  (const float*)d_in[10], (const float*)d_in[14]};

    const int B = 4096, N = 8192;
    const int NSPLIT = 8;

    // ---- workspace layout (floats) ----
    float* ws = (float*)d_ws;
    float* bufA = ws;                       // 8192*1024
    float* bufB = bufA + (size_t)8192*1024; // 8192*512
    float* KTb  = bufB + (size_t)8192*512;  // 256*8192 (K^T)
    float* q3   = KTb  + (size_t)256*8192;  // 4096*256
    float* stats= q3   + (size_t)4096*256;  // csum(1024)+csumsq(1024)+bacc(1024) -> zeroed
    float* csum = stats, *csumsq = stats + 1024, *bacc = stats + 2048;
    float* sbuf = stats + 3072;             // 1024
    float* tbuf = sbuf + 1024;              // 1024
    float* k2n  = tbuf + 1024;              // 8192
    float* pm   = k2n + 8192;               // 4096*NSPLIT
    float* pl   = pm + (size_t)B * NSPLIT;
    float* po   = pl + (size_t)B * NSPLIT;
    (void)ws_size; (void)n_in; (void)in_sizes; (void)out_size;

    auto run_layer = [&](const float* Xin, int R, int C, int F, int li,
                         float* Yout, bool trans) {
        hipMemsetAsync(stats, 0, 3072 * sizeof(float), stream);
        dim3 gs(C / 256, R / 512);
        col_stats<<<gs, 256, 0, stream>>>(Xin, csum, csumsq, R, C, 512);
        bn_prep<<<C / 256, 256, 0, stream>>>(csum, csumsq, gm[li], betam[li],
                                             sbuf, tbuf, C, 1.0f / (float)R);
        dim3 gf(F / 256, C / 128);
        fold_bias<<<gf, 256, 0, stream>>>(Wm[li], tbuf, bacc, C, F, 128);
        dim3 gg(R / 64, F / 64);
        if (trans)
            gemm_bn_tanh<true><<<gg, 256, 0, stream>>>(Xin, Wm[li], sbuf, bm[li], bacc, Yout, R, C, F);
        else
            gemm_bn_tanh<false><<<gg, 256, 0, stream>>>(Xin, Wm[li], sbuf, bm[li], bacc, Yout, R, C, F);
    };

    // k trunk (batch N=8192); layer 3 stores K^T [256][8192]
    run_layer(x_n,  N, 1024, 1024, 0, bufA, false);
    run_layer(bufA, N, 1024,  512, 1, bufB, false);
    run_layer(bufB, N,  512,  256, 2, KTb,  true);
    k2norm_k<<<N / 256, 256, 0, stream>>>(KTb, k2n, N);

    // q trunk (batch B=4096), reusing bufA/bufB
    run_layer(x,    B, 1024, 1024, 0, bufA, false);
    run_layer(bufA, B, 1024,  512, 1, bufB, false);
    run_layer(bufB, B,  512,  256, 2, q3,   false);

    // attention: logits = 2 Q.K^T - k2 ; softmax ; @ y_n ; clip
    dim3 gfl(B / 64, NSPLIT);
    flash_attn<<<gfl, 256, 0, stream>>>(q3, KTb, k2n, y_n, pm, pl, po,
                                        N, N / NSPLIT, NSPLIT);
    combine_k<<<(B + 255) / 256, 256, 0, stream>>>(pm, pl, po, (float*)d_out, B, NSPLIT);
}

// Round 3
// 1316.508 us; speedup vs baseline: 1.6046x; 1.6046x over previous
//
#include <hip/hip_runtime.h>
#include <math.h>
#include <stdint.h>

// ---------------------------------------------------------------------------
// fp16 MFMA version (bf16 failed accuracy: mantissa too short for the K=256
// sim dot; fp16 has 10 mantissa bits at the same MFMA rate).
// trunk layer: Y = tanh( Xh @ (s.W)h + b + t@W ),  s,t from batch stats.
// sim: logits = 2 Q.K^T - ||k||^2 (row-const -||q||^2 cancels in softmax),
// fused flash-style online softmax, V = y_n.
// All GEMMs: v_mfma_f32_16x16x32_f16, 128x128 tile, BK=32, global_load_lds.
// ---------------------------------------------------------------------------

typedef __attribute__((ext_vector_type(8))) _Float16 half8;
typedef __attribute__((ext_vector_type(4))) float floatx4;

__device__ __forceinline__ float fast_tanh(float x) {
    float ax = fabsf(x);
    float e  = __expf(-2.0f * ax);
    float r  = (1.0f - e) / (1.0f + e);
    return copysignf(r, x);
}
// async global->LDS, 16B per lane; LDS dest is wave-uniform base + lane*16
__device__ __forceinline__ void gload16(const void* g, void* l) {
    __builtin_amdgcn_global_load_lds(
        (__attribute__((address_space(1))) void*)(uintptr_t)(g),
        (__attribute__((address_space(3))) void*)(unsigned int)(uintptr_t)(l),
        16, 0, 0);
}

// -------- fp32 -> fp16 convert (8 elems/thread, 16B store) -----------------
__global__ void tof16(const float* __restrict__ in, _Float16* __restrict__ out, int n8) {
    int i = blockIdx.x * blockDim.x + threadIdx.x;
    if (i >= n8) return;
    float4 a = *(const float4*)&in[(size_t)i * 8];
    float4 b = *(const float4*)&in[(size_t)i * 8 + 4];
    half8 h;
    h[0] = (_Float16)a.x; h[1] = (_Float16)a.y; h[2] = (_Float16)a.z; h[3] = (_Float16)a.w;
    h[4] = (_Float16)b.x; h[5] = (_Float16)b.y; h[6] = (_Float16)b.z; h[7] = (_Float16)b.w;
    *(half8*)&out[(size_t)i * 8] = h;
}

// -------- per-column mean/meansq partial sums ------------------------------
__global__ void col_stats_f32(const float* __restrict__ X, float* __restrict__ csum,
                              float* __restrict__ csumsq, int R, int C, int rpb) {
    int c  = blockIdx.x * blockDim.x + threadIdx.x;
    int r0 = blockIdx.y * rpb, r1 = r0 + rpb; if (r1 > R) r1 = R;
    float s = 0.f, q = 0.f;
    for (int r = r0; r < r1; ++r) {
        float v = X[(size_t)r * C + c];
        s += v; q += v * v;
    }
    atomicAdd(&csum[c], s);
    atomicAdd(&csumsq[c], q);
}
__global__ void col_stats_f16(const _Float16* __restrict__ X, float* __restrict__ csum,
                              float* __restrict__ csumsq, int R, int C, int rpb) {
    int c  = blockIdx.x * blockDim.x + threadIdx.x;
    int r0 = blockIdx.y * rpb, r1 = r0 + rpb; if (r1 > R) r1 = R;
    float s = 0.f, q = 0.f;
    for (int r = r0; r < r1; ++r) {
        float v = (float)X[(size_t)r * C + c];
        s += v; q += v * v;
    }
    atomicAdd(&csum[c], s);
    atomicAdd(&csumsq[c], q);
}

// -------- BN fold: s = g*rsqrt(var+eps), t = beta - mean*s -----------------
__global__ void bn_prep(const float* __restrict__ csum, const float* __restrict__ csumsq,
                        const float* __restrict__ g, const float* __restrict__ beta,
                        float* __restrict__ s_out, float* __restrict__ t_out,
                        int C, float invR) {
    int c = blockIdx.x * blockDim.x + threadIdx.x;
    if (c >= C) return;
    float mean = csum[c] * invR;
    float var  = fmaxf(csumsq[c] * invR - mean * mean, 0.f);
    float s    = g[c] * rsqrtf(var + 1e-5f);
    s_out[c] = s;
    t_out[c] = beta[c] - mean * s;
}

// -------- bias correction: bacc[f] += sum_c t[c]*W[c][f] (fp32) ------------
__global__ void fold_bias(const float* __restrict__ W, const float* __restrict__ t_,
                          float* __restrict__ bacc, int C, int F, int cch) {
    int f  = blockIdx.x * blockDim.x + threadIdx.x;
    int c0 = blockIdx.y * cch;
    float acc = 0.f;
    for (int c = c0; c < c0 + cch; ++c)
        acc += t_[c] * W[(size_t)c * F + f];
    atomicAdd(&bacc[f], acc);
}

// -------- W'T[f][c] = fp16(s[c]*W[c][f]) : scaled transpose ----------------
__global__ void wprep(const float* __restrict__ W, const float* __restrict__ s_,
                      _Float16* __restrict__ WT, int C, int F) {
    __shared__ float tile[32][33];
    int c0 = blockIdx.y * 32, f0 = blockIdx.x * 32;
    int tx = threadIdx.x & 31, ty = threadIdx.x >> 5;   // 32x8
#pragma unroll
    for (int i = 0; i < 32; i += 8)
        tile[ty + i][tx] = W[(size_t)(c0 + ty + i) * F + f0 + tx] * s_[c0 + ty + i];
    __syncthreads();
#pragma unroll
    for (int i = 0; i < 32; i += 8)
        WT[(size_t)(f0 + ty + i) * C + c0 + tx] = (_Float16)tile[tx][ty + i];
}

// -------- TN fp16 MFMA GEMM + bias + tanh -> fp16 out ----------------------
// A [M][K], BT [N][K] ; Y[i][f] = tanh(sum_k A.B + bias[f]+bacc[f])
__global__ __launch_bounds__(256) void gemm_tn_tanh(
        const _Float16* __restrict__ A, const _Float16* __restrict__ BT,
        const float* __restrict__ bias, const float* __restrict__ bacc,
        _Float16* __restrict__ Y, int M, int K, int N) {
    __shared__ _Float16 As[128 * 32];
    __shared__ _Float16 Bs[128 * 32];
    const int tid = threadIdx.x;
    const int wv = tid >> 6, ln = tid & 63;
    const int quad = ln >> 4, l16 = ln & 15;
    const int wr = wv >> 1, wc = wv & 1;
    const int i0 = blockIdx.x * 128, f0 = blockIdx.y * 128;

    floatx4 acc[4][4];
#pragma unroll
    for (int a = 0; a < 4; ++a)
#pragma unroll
        for (int b = 0; b < 4; ++b) acc[a][b] = (floatx4)0.f;

    for (int k0 = 0; k0 < K; k0 += 32) {
        const _Float16* Ab = A + (size_t)i0 * K + k0;
        const _Float16* Bb = BT + (size_t)f0 * K + k0;
#pragma unroll
        for (int is = 0; is < 2; ++is) {
            int ch = is * 256 + tid;                     // chunk id: row=ch>>2, 16B seg=ch&3
            gload16((const char*)Ab + (size_t)(ch >> 2) * K * 2 + (ch & 3) * 16,
                    (char*)As + (is * 256 + wv * 64) * 16);
            gload16((const char*)Bb + (size_t)(ch >> 2) * K * 2 + (ch & 3) * 16,
                    (char*)Bs + (is * 256 + wv * 64) * 16);
        }
        __syncthreads();
        half8 af[4], bfr[4];
#pragma unroll
        for (int t = 0; t < 4; ++t) {
            af[t]  = *(const half8*)(As + (wr * 64 + t * 16 + l16) * 32 + quad * 8);
            bfr[t] = *(const half8*)(Bs + (wc * 64 + t * 16 + l16) * 32 + quad * 8);
        }
#pragma unroll
        for (int tr = 0; tr < 4; ++tr)
#pragma unroll
            for (int tc = 0; tc < 4; ++tc)
                acc[tr][tc] = __builtin_amdgcn_mfma_f32_16x16x32_f16(af[tr], bfr[tc], acc[tr][tc], 0, 0, 0);
        __syncthreads();
    }
#pragma unroll
    for (int tc = 0; tc < 4; ++tc) {
        int f = f0 + wc * 64 + tc * 16 + l16;
        float bb = bias[f] + bacc[f];
#pragma unroll
        for (int tr = 0; tr < 4; ++tr)
#pragma unroll
            for (int r = 0; r < 4; ++r) {
                int row = i0 + wr * 64 + tr * 16 + quad * 4 + r;
                Y[(size_t)row * N + f] = (_Float16)fast_tanh(acc[tr][tc][r] + bb);
            }
    }
}

// -------- ||k_j||^2 from fp16 K3 [N][256] ----------------------------------
__global__ void k2norm(const _Float16* __restrict__ K3, float* __restrict__ k2n, int NJ) {
    int j  = blockIdx.x * 4 + (threadIdx.x >> 6);
    int ln = threadIdx.x & 63;
    const _Float16* row = K3 + (size_t)j * 256 + ln * 4;
    float acc = 0.f;
#pragma unroll
    for (int d = 0; d < 4; ++d) {
        float v = (float)row[d];
        acc += v * v;
    }
#pragma unroll
    for (int m = 1; m < 64; m <<= 1) acc += __shfl_xor(acc, m);
    if (ln == 0) k2n[j] = acc;
}

// -------- MFMA flash: S = Q.K^T (K=256), logits = 2S - k2, online softmax --
// block: 128 q-rows; wave wv owns rows wv*32..+32 and ALL 128 cols of a chunk.
__global__ __launch_bounds__(256) void flash_mfma(
        const _Float16* __restrict__ Q, const _Float16* __restrict__ K3,
        const float* __restrict__ k2n, const float* __restrict__ yv,
        float* __restrict__ pm, float* __restrict__ pl, float* __restrict__ po,
        int NJ, int jlen, int nsplit) {
    __shared__ _Float16 Qs[128 * 32];
    __shared__ _Float16 Ks[128 * 32];
    const int tid = threadIdx.x;
    const int wv = tid >> 6, ln = tid & 63;
    const int quad = ln >> 4, l16 = ln & 15;
    const int i0 = blockIdx.x * 128;
    const int jb = blockIdx.y * jlen;

    float mrun[2][4], lrun[2][4], orun[2][4];
#pragma unroll
    for (int tr = 0; tr < 2; ++tr)
#pragma unroll
        for (int r = 0; r < 4; ++r) { mrun[tr][r] = -INFINITY; lrun[tr][r] = 0.f; orun[tr][r] = 0.f; }

    for (int j0 = jb; j0 < jb + jlen; j0 += 128) {
        floatx4 acc[2][8];
#pragma unroll
        for (int a = 0; a < 2; ++a)
#pragma unroll
            for (int b = 0; b < 8; ++b) acc[a][b] = (floatx4)0.f;

        for (int k0 = 0; k0 < 256; k0 += 32) {
            const _Float16* Qb = Q + (size_t)i0 * 256 + k0;
            const _Float16* Kb = K3 + (size_t)j0 * 256 + k0;
#pragma unroll
            for (int is = 0; is < 2; ++is) {
                int ch = is * 256 + tid;
                gload16((const char*)Qb + (size_t)(ch >> 2) * 512 + (ch & 3) * 16,
                        (char*)Qs + (is * 256 + wv * 64) * 16);
                gload16((const char*)Kb + (size_t)(ch >> 2) * 512 + (ch & 3) * 16,
                        (char*)Ks + (is * 256 + wv * 64) * 16);
            }
            __syncthreads();
            half8 qf[2], kf[8];
#pragma unroll
            for (int t = 0; t < 2; ++t)
                qf[t] = *(const half8*)(Qs + (wv * 32 + t * 16 + l16) * 32 + quad * 8);
#pragma unroll
            for (int t = 0; t < 8; ++t)
                kf[t] = *(const half8*)(Ks + (t * 16 + l16) * 32 + quad * 8);
#pragma unroll
            for (int tr = 0; tr < 2; ++tr)
#pragma unroll
                for (int tc = 0; tc < 8; ++tc)
                    acc[tr][tc] = __builtin_amdgcn_mfma_f32_16x16x32_f16(qf[tr], kf[tc], acc[tr][tc], 0, 0, 0);
            __syncthreads();
        }
        // online softmax over this 128-col chunk
        float k2v[8], yv8[8];
#pragma unroll
        for (int tc = 0; tc < 8; ++tc) {
            int j = j0 + tc * 16 + l16;
            k2v[tc] = k2n[j];
            yv8[tc] = yv[j];
        }
#pragma unroll
        for (int tr = 0; tr < 2; ++tr)
#pragma unroll
            for (int r = 0; r < 4; ++r) {
                float lg[8], mt = -INFINITY;
#pragma unroll
                for (int tc = 0; tc < 8; ++tc) {
                    lg[tc] = 2.f * acc[tr][tc][r] - k2v[tc];
                    mt = fmaxf(mt, lg[tc]);
                }
#pragma unroll
                for (int m = 1; m < 16; m <<= 1) mt = fmaxf(mt, __shfl_xor(mt, m));
                float mnew = fmaxf(mrun[tr][r], mt);
                float sp = 0.f, spy = 0.f;
#pragma unroll
                for (int tc = 0; tc < 8; ++tc) {
                    float p = __expf(lg[tc] - mnew);
                    sp  += p;
                    spy += p * yv8[tc];
                }
#pragma unroll
                for (int m = 1; m < 16; m <<= 1) {
                    sp  += __shfl_xor(sp, m);
                    spy += __shfl_xor(spy, m);
                }
                float sc = __expf(mrun[tr][r] - mnew);   // exp(-inf)=0 first time
                lrun[tr][r] = lrun[tr][r] * sc + sp;
                orun[tr][r] = orun[tr][r] * sc + spy;
                mrun[tr][r] = mnew;
            }
    }
    if (l16 == 0) {
#pragma unroll
        for (int tr = 0; tr < 2; ++tr)
#pragma unroll
            for (int r = 0; r < 4; ++r) {
                int row = i0 + wv * 32 + tr * 16 + quad * 4 + r;
                size_t idx = (size_t)row * nsplit + blockIdx.y;
                pm[idx] = mrun[tr][r];
                pl[idx] = lrun[tr][r];
                po[idx] = orun[tr][r];
            }
    }
}

// -------- combine j-split partials -----------------------------------------
__global__ void combine_k(const float* __restrict__ pm, const float* __restrict__ pl,
                          const float* __restrict__ po, float* __restrict__ out,
                          int B, int nsplit) {
    int i = blockIdx.x * blockDim.x + threadIdx.x;
    if (i >= B) return;
    float M = -INFINITY;
    for (int s = 0; s < nsplit; ++s) M = fmaxf(M, pm[(size_t)i * nsplit + s]);
    float L = 0.f, O = 0.f;
    for (int s = 0; s < nsplit; ++s) {
        float w = __expf(pm[(size_t)i * nsplit + s] - M);
        L += pl[(size_t)i * nsplit + s] * w;
        O += po[(size_t)i * nsplit + s] * w;
    }
    float r = O / L;
    out[i] = fminf(fmaxf(r, 0.f), 1.f);
}

// ---------------------------------------------------------------------------
extern "C" void kernel_launch(void* const* d_in, const int* in_sizes, int n_in,
                              void* d_out, int out_size, void* d_ws, size_t ws_size,
                              hipStream_t stream) {
    const float* x   = (const float*)d_in[0];   // [4096,1024]
    const float* x_n = (const float*)d_in[1];   // [8192,1024]
    const float* y_n = (const float*)d_in[2];   // [8192,1]
    const float* Wm[3]    = {(const float*)d_in[3],  (const float*)d_in[7],  (const float*)d_in[11]};
    const float* bm[3]    = {(const float*)d_in[4],  (const float*)d_in[8],  (const float*)d_in[12]};
    const float* gm[3]    = {(const float*)d_in[5],  (const float*)d_in[9],  (const float*)d_in[13]};
    const float* betam[3] = {(const float*)d_in[6],  (const float*)d_in[10], (const float*)d_in[14]};
    (void)in_sizes; (void)n_in; (void)out_size; (void)ws_size;

    const int B = 4096, N = 8192;
    const int NSPLIT = 16;

    // ---- workspace layout ----
    _Float16* xnh  = (_Float16*)d_ws;                  // 8192*1024
    _Float16* xh   = xnh  + (size_t)8192 * 1024;       // 4096*1024
    _Float16* actA = xh   + (size_t)4096 * 1024;       // 8192*1024 (reused)
    _Float16* actB = actA + (size_t)8192 * 1024;       // 8192*512
    _Float16* k3   = actB + (size_t)8192 * 512;        // 8192*256
    _Float16* q3   = k3   + (size_t)8192 * 256;        // 4096*256
    _Float16* WT   = q3   + (size_t)4096 * 256;        // 1024*1024
    float* fb    = (float*)(WT + (size_t)1024 * 1024);
    float* csum  = fb;            // 1024
    float* csumsq= fb + 1024;     // 1024
    float* bacc  = fb + 2048;     // 1024
    float* sbuf  = fb + 3072;     // 1024
    float* tbuf  = fb + 4096;     // 1024
    float* k2n   = fb + 5120;     // 8192
    float* pm    = fb + 5120 + 8192;                 // 4096*NSPLIT
    float* pl    = pm + (size_t)B * NSPLIT;
    float* po    = pl + (size_t)B * NSPLIT;

    auto run_layer = [&](const float* Xf32, const _Float16* Xh,
                         int R, int C, int F, int li, _Float16* Yout) {
        hipMemsetAsync(csum, 0, 3072 * sizeof(float), stream);
        dim3 gs(C / 256, R / 512);
        if (Xf32) col_stats_f32<<<gs, 256, 0, stream>>>(Xf32, csum, csumsq, R, C, 512);
        else      col_stats_f16<<<gs, 256, 0, stream>>>(Xh,   csum, csumsq, R, C, 512);
        bn_prep<<<C / 256, 256, 0, stream>>>(csum, csumsq, gm[li], betam[li], sbuf, tbuf, C, 1.0f / (float)R);
        fold_bias<<<dim3(F / 256, C / 128), 256, 0, stream>>>(Wm[li], tbuf, bacc, C, F, 128);
        wprep<<<dim3(F / 32, C / 32), 256, 0, stream>>>(Wm[li], sbuf, WT, C, F);
        gemm_tn_tanh<<<dim3(R / 128, F / 128), 256, 0, stream>>>(Xh, WT, bm[li], bacc, Yout, R, C, F);
    };

    // convert inputs to fp16
    tof16<<<(N * 1024 / 8) / 256, 256, 0, stream>>>(x_n, xnh, N * 1024 / 8);
    tof16<<<(B * 1024 / 8) / 256, 256, 0, stream>>>(x,   xh,  B * 1024 / 8);

    // k trunk (N=8192)
    run_layer(x_n,     xnh,  N, 1024, 1024, 0, actA);
    run_layer(nullptr, actA, N, 1024,  512, 1, actB);
    run_layer(nullptr, actB, N,  512,  256, 2, k3);
    k2norm<<<N / 4, 256, 0, stream>>>(k3, k2n, N);

    // q trunk (B=4096), reuse actA/actB
    run_layer(x,       xh,   B, 1024, 1024, 0, actA);
    run_layer(nullptr, actA, B, 1024,  512, 1, actB);
    run_layer(nullptr, actB, B,  512,  256, 2, q3);

    // fused attention
    flash_mfma<<<dim3(B / 128, NSPLIT), 256, 0, stream>>>(q3, k3, k2n, y_n, pm, pl, po,
                                                          N, N / NSPLIT, NSPLIT);
    combine_k<<<B / 256, 256, 0, stream>>>(pm, pl, po, (float*)d_out, B, NSPLIT);
}

// Round 4
// 417.964 us; speedup vs baseline: 5.0543x; 3.1498x over previous
//
#include <hip/hip_runtime.h>
#include <math.h>
#include <stdint.h>

// ---------------------------------------------------------------------------
// fp16 MFMA, fused-stats version.
// R3 post-mortem: 6x col_stats_f16 dispatches were 830us of 1316us (latency-
// bound: 1 wave/CU, scalar fp16 loads). Fix: BN column stats are computed by
// whoever PRODUCES the activation: layer-1 stats fused into the fp32->fp16
// convert; layer-2/3 stats fused into the upstream GEMM epilogue (values are
// already in registers). fold_bias fused into wprep (same W stream);
// ||k||^2 fused into the k-trunk L3 GEMM epilogue (row sumsq).
// ---------------------------------------------------------------------------

typedef __attribute__((ext_vector_type(8))) _Float16 half8;
typedef __attribute__((ext_vector_type(4))) _Float16 half4;
typedef __attribute__((ext_vector_type(4))) float floatx4;

__device__ __forceinline__ float fast_tanh(float x) {
    float ax = fabsf(x);
    float e  = __expf(-2.0f * ax);
    float r  = (1.0f - e) / (1.0f + e);
    return copysignf(r, x);
}
// async global->LDS, 16B per lane; LDS dest is wave-uniform base + lane*16
__device__ __forceinline__ void gload16(const void* g, void* l) {
    __builtin_amdgcn_global_load_lds(
        (__attribute__((address_space(1))) void*)(uintptr_t)(g),
        (__attribute__((address_space(3))) void*)(unsigned int)(uintptr_t)(l),
        16, 0, 0);
}

// -------- fp32 -> fp16 convert + column stats (C = 1024 fixed) -------------
// 256 threads = 4 cols/thread = one full row per iteration; rpb rows/block.
__global__ __launch_bounds__(256) void tof16_stats(
        const float* __restrict__ in, _Float16* __restrict__ out,
        float* __restrict__ csum, float* __restrict__ csumsq, int rpb) {
    const int r0 = blockIdx.x * rpb;
    const int c  = threadIdx.x * 4;
    float s0 = 0.f, s1 = 0.f, s2 = 0.f, s3 = 0.f;
    float q0 = 0.f, q1 = 0.f, q2 = 0.f, q3 = 0.f;
    for (int r = r0; r < r0 + rpb; ++r) {
        float4 v = *(const float4*)&in[(size_t)r * 1024 + c];
        half4 h;
        h[0] = (_Float16)v.x; h[1] = (_Float16)v.y;
        h[2] = (_Float16)v.z; h[3] = (_Float16)v.w;
        *(half4*)&out[(size_t)r * 1024 + c] = h;
        s0 += v.x; q0 += v.x * v.x;
        s1 += v.y; q1 += v.y * v.y;
        s2 += v.z; q2 += v.z * v.z;
        s3 += v.w; q3 += v.w * v.w;
    }
    atomicAdd(&csum[c + 0], s0); atomicAdd(&csumsq[c + 0], q0);
    atomicAdd(&csum[c + 1], s1); atomicAdd(&csumsq[c + 1], q1);
    atomicAdd(&csum[c + 2], s2); atomicAdd(&csumsq[c + 2], q2);
    atomicAdd(&csum[c + 3], s3); atomicAdd(&csumsq[c + 3], q3);
}

// -------- BN fold: s = g*rsqrt(var+eps), t = beta - mean*s -----------------
__global__ void bn_prep(const float* __restrict__ csum, const float* __restrict__ csumsq,
                        const float* __restrict__ g, const float* __restrict__ beta,
                        float* __restrict__ s_out, float* __restrict__ t_out,
                        int C, float invR) {
    int c = blockIdx.x * blockDim.x + threadIdx.x;
    if (c >= C) return;
    float mean = csum[c] * invR;
    float var  = fmaxf(csumsq[c] * invR - mean * mean, 0.f);
    float s    = g[c] * rsqrtf(var + 1e-5f);
    s_out[c] = s;
    t_out[c] = beta[c] - mean * s;
}

// -------- W'T[f][c] = fp16(s[c]*W[c][f]) + bias fold bacc[f] += t@W --------
__global__ __launch_bounds__(256) void wprep(
        const float* __restrict__ W, const float* __restrict__ s_,
        const float* __restrict__ t_, _Float16* __restrict__ WT,
        float* __restrict__ bacc, int C, int F) {
    __shared__ float tile[32][33];
    __shared__ float lds2[8][32];
    const int c0 = blockIdx.y * 32, f0 = blockIdx.x * 32;
    const int tx = threadIdx.x & 31, ty = threadIdx.x >> 5;   // 32x8
    float pacc = 0.f;
#pragma unroll
    for (int i = 0; i < 32; i += 8) {
        float w = W[(size_t)(c0 + ty + i) * F + f0 + tx];
        tile[ty + i][tx] = w * s_[c0 + ty + i];
        pacc += w * t_[c0 + ty + i];
    }
    lds2[ty][tx] = pacc;
    __syncthreads();
#pragma unroll
    for (int i = 0; i < 32; i += 8)
        WT[(size_t)(f0 + ty + i) * C + c0 + tx] = (_Float16)tile[tx][ty + i];
    if (ty == 0) {
        float a = 0.f;
#pragma unroll
        for (int j = 0; j < 8; ++j) a += lds2[j][tx];
        atomicAdd(&bacc[f0 + tx], a);
    }
}

// -------- TN fp16 MFMA GEMM + bias + tanh -> fp16 out ----------------------
// SMODE: 0 = plain, 1 = emit column stats (next layer BN), 2 = emit row sumsq
__global__ __launch_bounds__(256) void gemm_tn_tanh(
        const _Float16* __restrict__ A, const _Float16* __restrict__ BT,
        const float* __restrict__ bias, const float* __restrict__ bacc,
        _Float16* __restrict__ Y, int M, int K, int N, int SMODE,
        float* __restrict__ csum_n, float* __restrict__ csumsq_n,
        float* __restrict__ rowsq) {
    __shared__ _Float16 As[128 * 32];
    __shared__ _Float16 Bs[128 * 32];
    const int tid = threadIdx.x;
    const int wv = tid >> 6, ln = tid & 63;
    const int quad = ln >> 4, l16 = ln & 15;
    const int wr = wv >> 1, wc = wv & 1;
    const int i0 = blockIdx.x * 128, f0 = blockIdx.y * 128;

    floatx4 acc[4][4];
#pragma unroll
    for (int a = 0; a < 4; ++a)
#pragma unroll
        for (int b = 0; b < 4; ++b) acc[a][b] = (floatx4)0.f;

    for (int k0 = 0; k0 < K; k0 += 32) {
        const _Float16* Ab = A + (size_t)i0 * K + k0;
        const _Float16* Bb = BT + (size_t)f0 * K + k0;
#pragma unroll
        for (int is = 0; is < 2; ++is) {
            int ch = is * 256 + tid;                     // row=ch>>2, 16B seg=ch&3
            gload16((const char*)Ab + (size_t)(ch >> 2) * K * 2 + (ch & 3) * 16,
                    (char*)As + (is * 256 + wv * 64) * 16);
            gload16((const char*)Bb + (size_t)(ch >> 2) * K * 2 + (ch & 3) * 16,
                    (char*)Bs + (is * 256 + wv * 64) * 16);
        }
        __syncthreads();
        half8 af[4], bfr[4];
#pragma unroll
        for (int t = 0; t < 4; ++t) {
            af[t]  = *(const half8*)(As + (wr * 64 + t * 16 + l16) * 32 + quad * 8);
            bfr[t] = *(const half8*)(Bs + (wc * 64 + t * 16 + l16) * 32 + quad * 8);
        }
#pragma unroll
        for (int tr = 0; tr < 4; ++tr)
#pragma unroll
            for (int tc = 0; tc < 4; ++tc)
                acc[tr][tc] = __builtin_amdgcn_mfma_f32_16x16x32_f16(af[tr], bfr[tc], acc[tr][tc], 0, 0, 0);
        __syncthreads();
    }
    // epilogue: tanh + store; keep activations in acc for the stats pass
#pragma unroll
    for (int tc = 0; tc < 4; ++tc) {
        int f = f0 + wc * 64 + tc * 16 + l16;
        float bb = bias[f] + bacc[f];
#pragma unroll
        for (int tr = 0; tr < 4; ++tr)
#pragma unroll
            for (int r = 0; r < 4; ++r) {
                int row = i0 + wr * 64 + tr * 16 + quad * 4 + r;
                float v = fast_tanh(acc[tr][tc][r] + bb);
                acc[tr][tc][r] = v;
                Y[(size_t)row * N + f] = (_Float16)v;
            }
    }
    if (SMODE == 1) {   // per-column sum / sumsq for next layer's BN
#pragma unroll
        for (int tc = 0; tc < 4; ++tc) {
            int f = f0 + wc * 64 + tc * 16 + l16;
            float cs = 0.f, cq = 0.f;
#pragma unroll
            for (int tr = 0; tr < 4; ++tr)
#pragma unroll
                for (int r = 0; r < 4; ++r) {
                    float v = acc[tr][tc][r];
                    cs += v; cq += v * v;
                }
            cs += __shfl_xor(cs, 16); cq += __shfl_xor(cq, 16);
            cs += __shfl_xor(cs, 32); cq += __shfl_xor(cq, 32);
            if (quad == 0) {
                atomicAdd(&csum_n[f], cs);
                atomicAdd(&csumsq_n[f], cq);
            }
        }
    } else if (SMODE == 2) {   // per-row sumsq (||k_j||^2)
#pragma unroll
        for (int tr = 0; tr < 4; ++tr)
#pragma unroll
            for (int r = 0; r < 4; ++r) {
                float rq = 0.f;
#pragma unroll
                for (int tc = 0; tc < 4; ++tc) {
                    float v = acc[tr][tc][r];
                    rq += v * v;
                }
                rq += __shfl_xor(rq, 1); rq += __shfl_xor(rq, 2);
                rq += __shfl_xor(rq, 4); rq += __shfl_xor(rq, 8);
                if (l16 == 0)
                    atomicAdd(&rowsq[i0 + wr * 64 + tr * 16 + quad * 4 + r], rq);
            }
    }
}

// -------- MFMA flash: S = Q.K^T (K=256), logits = 2S - k2, online softmax --
__global__ __launch_bounds__(256) void flash_mfma(
        const _Float16* __restrict__ Q, const _Float16* __restrict__ K3,
        const float* __restrict__ k2n, const float* __restrict__ yv,
        float* __restrict__ pm, float* __restrict__ pl, float* __restrict__ po,
        int NJ, int jlen, int nsplit) {
    __shared__ _Float16 Qs[128 * 32];
    __shared__ _Float16 Ks[128 * 32];
    const int tid = threadIdx.x;
    const int wv = tid >> 6, ln = tid & 63;
    const int quad = ln >> 4, l16 = ln & 15;
    const int i0 = blockIdx.x * 128;
    const int jb = blockIdx.y * jlen;

    float mrun[2][4], lrun[2][4], orun[2][4];
#pragma unroll
    for (int tr = 0; tr < 2; ++tr)
#pragma unroll
        for (int r = 0; r < 4; ++r) { mrun[tr][r] = -INFINITY; lrun[tr][r] = 0.f; orun[tr][r] = 0.f; }

    for (int j0 = jb; j0 < jb + jlen; j0 += 128) {
        floatx4 acc[2][8];
#pragma unroll
        for (int a = 0; a < 2; ++a)
#pragma unroll
            for (int b = 0; b < 8; ++b) acc[a][b] = (floatx4)0.f;

        for (int k0 = 0; k0 < 256; k0 += 32) {
            const _Float16* Qb = Q + (size_t)i0 * 256 + k0;
            const _Float16* Kb = K3 + (size_t)j0 * 256 + k0;
#pragma unroll
            for (int is = 0; is < 2; ++is) {
                int ch = is * 256 + tid;
                gload16((const char*)Qb + (size_t)(ch >> 2) * 512 + (ch & 3) * 16,
                        (char*)Qs + (is * 256 + wv * 64) * 16);
                gload16((const char*)Kb + (size_t)(ch >> 2) * 512 + (ch & 3) * 16,
                        (char*)Ks + (is * 256 + wv * 64) * 16);
            }
            __syncthreads();
            half8 qf[2], kf[8];
#pragma unroll
            for (int t = 0; t < 2; ++t)
                qf[t] = *(const half8*)(Qs + (wv * 32 + t * 16 + l16) * 32 + quad * 8);
#pragma unroll
            for (int t = 0; t < 8; ++t)
                kf[t] = *(const half8*)(Ks + (t * 16 + l16) * 32 + quad * 8);
#pragma unroll
            for (int tr = 0; tr < 2; ++tr)
#pragma unroll
                for (int tc = 0; tc < 8; ++tc)
                    acc[tr][tc] = __builtin_amdgcn_mfma_f32_16x16x32_f16(qf[tr], kf[tc], acc[tr][tc], 0, 0, 0);
            __syncthreads();
        }
        float k2v[8], yv8[8];
#pragma unroll
        for (int tc = 0; tc < 8; ++tc) {
            int j = j0 + tc * 16 + l16;
            k2v[tc] = k2n[j];
            yv8[tc] = yv[j];
        }
#pragma unroll
        for (int tr = 0; tr < 2; ++tr)
#pragma unroll
            for (int r = 0; r < 4; ++r) {
                float lg[8], mt = -INFINITY;
#pragma unroll
                for (int tc = 0; tc < 8; ++tc) {
                    lg[tc] = 2.f * acc[tr][tc][r] - k2v[tc];
                    mt = fmaxf(mt, lg[tc]);
                }
#pragma unroll
                for (int m = 1; m < 16; m <<= 1) mt = fmaxf(mt, __shfl_xor(mt, m));
                float mnew = fmaxf(mrun[tr][r], mt);
                float sp = 0.f, spy = 0.f;
#pragma unroll
                for (int tc = 0; tc < 8; ++tc) {
                    float p = __expf(lg[tc] - mnew);
                    sp  += p;
                    spy += p * yv8[tc];
                }
#pragma unroll
                for (int m = 1; m < 16; m <<= 1) {
                    sp  += __shfl_xor(sp, m);
                    spy += __shfl_xor(spy, m);
                }
                float sc = __expf(mrun[tr][r] - mnew);   // exp(-inf)=0 first time
                lrun[tr][r] = lrun[tr][r] * sc + sp;
                orun[tr][r] = orun[tr][r] * sc + spy;
                mrun[tr][r] = mnew;
            }
    }
    if (l16 == 0) {
#pragma unroll
        for (int tr = 0; tr < 2; ++tr)
#pragma unroll
            for (int r = 0; r < 4; ++r) {
                int row = i0 + wv * 32 + tr * 16 + quad * 4 + r;
                size_t idx = (size_t)row * nsplit + blockIdx.y;
                pm[idx] = mrun[tr][r];
                pl[idx] = lrun[tr][r];
                po[idx] = orun[tr][r];
            }
    }
}

// -------- combine j-split partials -----------------------------------------
__global__ void combine_k(const float* __restrict__ pm, const float* __restrict__ pl,
                          const float* __restrict__ po, float* __restrict__ out,
                          int B, int nsplit) {
    int i = blockIdx.x * blockDim.x + threadIdx.x;
    if (i >= B) return;
    float M = -INFINITY;
    for (int s = 0; s < nsplit; ++s) M = fmaxf(M, pm[(size_t)i * nsplit + s]);
    float L = 0.f, O = 0.f;
    for (int s = 0; s < nsplit; ++s) {
        float w = __expf(pm[(size_t)i * nsplit + s] - M);
        L += pl[(size_t)i * nsplit + s] * w;
        O += po[(size_t)i * nsplit + s] * w;
    }
    float r = O / L;
    out[i] = fminf(fmaxf(r, 0.f), 1.f);
}

// ---------------------------------------------------------------------------
extern "C" void kernel_launch(void* const* d_in, const int* in_sizes, int n_in,
                              void* d_out, int out_size, void* d_ws, size_t ws_size,
                              hipStream_t stream) {
    const float* x   = (const float*)d_in[0];   // [4096,1024]
    const float* x_n = (const float*)d_in[1];   // [8192,1024]
    const float* y_n = (const float*)d_in[2];   // [8192,1]
    const float* Wm[3]    = {(const float*)d_in[3],  (const float*)d_in[7],  (const float*)d_in[11]};
    const float* bm[3]    = {(const float*)d_in[4],  (const float*)d_in[8],  (const float*)d_in[12]};
    const float* gm[3]    = {(const float*)d_in[5],  (const float*)d_in[9],  (const float*)d_in[13]};
    const float* betam[3] = {(const float*)d_in[6],  (const float*)d_in[10], (const float*)d_in[14]};
    (void)in_sizes; (void)n_in; (void)out_size; (void)ws_size;

    const int B = 4096, N = 8192;
    const int NSPLIT = 16;

    // ---- workspace layout ----
    _Float16* xnh  = (_Float16*)d_ws;                  // 8192*1024
    _Float16* xh   = xnh  + (size_t)8192 * 1024;       // 4096*1024
    _Float16* actA = xh   + (size_t)4096 * 1024;       // 8192*1024 (reused)
    _Float16* actB = actA + (size_t)8192 * 1024;       // 8192*512
    _Float16* k3   = actB + (size_t)8192 * 512;        // 8192*256
    _Float16* q3   = k3   + (size_t)8192 * 256;        // 4096*256
    _Float16* WT   = q3   + (size_t)4096 * 256;        // 1024*1024
    float* fb = (float*)(WT + (size_t)1024 * 1024);
    // zeroed region: 6 stat sets (csum+csumsq) + 6 bacc + k2n
    float* csumA[6], *csumsqA[6], *baccA[6];
    for (int i = 0; i < 6; ++i) {
        csumA[i]   = fb + i * 2048;
        csumsqA[i] = fb + i * 2048 + 1024;
        baccA[i]   = fb + 12288 + i * 1024;
    }
    float* k2n = fb + 12288 + 6144;                    // 8192
    const size_t zero_floats = 12288 + 6144 + 8192;
    float* sbuf = k2n + 8192;        // 1024 (rotating, produced+consumed in seq)
    float* tbuf = sbuf + 1024;       // 1024
    float* pm   = tbuf + 1024;       // B*NSPLIT
    float* pl   = pm + (size_t)B * NSPLIT;
    float* po   = pl + (size_t)B * NSPLIT;

    hipMemsetAsync(fb, 0, zero_floats * sizeof(float), stream);

    // run one trunk layer: BN-fold from stat set si, GEMM emits stats per mode
    auto run_layer = [&](const _Float16* Xh, int R, int C, int F, int li, int si,
                         _Float16* Yout, int smode, float* cs_n, float* cq_n, float* rsq) {
        bn_prep<<<C / 256, 256, 0, stream>>>(csumA[si], csumsqA[si], gm[li], betam[li],
                                             sbuf, tbuf, C, 1.0f / (float)R);
        wprep<<<dim3(F / 32, C / 32), 256, 0, stream>>>(Wm[li], sbuf, tbuf, WT, baccA[si], C, F);
        gemm_tn_tanh<<<dim3(R / 128, F / 128), 256, 0, stream>>>(
            Xh, WT, bm[li], baccA[si], Yout, R, C, F, smode, cs_n, cq_n, rsq);
    };

    // input convert + layer-1 stats (fp32 source)
    tof16_stats<<<N / 32, 256, 0, stream>>>(x_n, xnh, csumA[0], csumsqA[0], 32);
    tof16_stats<<<B / 32, 256, 0, stream>>>(x,   xh,  csumA[3], csumsqA[3], 32);

    // k trunk (N=8192): L1 -> stats set1, L2 -> set2, L3 -> k2n
    run_layer(xnh,  N, 1024, 1024, 0, 0, actA, 1, csumA[1], csumsqA[1], nullptr);
    run_layer(actA, N, 1024,  512, 1, 1, actB, 1, csumA[2], csumsqA[2], nullptr);
    run_layer(actB, N,  512,  256, 2, 2, k3,   2, nullptr,  nullptr,    k2n);

    // q trunk (B=4096): L1 -> set4, L2 -> set5, L3 plain
    run_layer(xh,   B, 1024, 1024, 0, 3, actA, 1, csumA[4], csumsqA[4], nullptr);
    run_layer(actA, B, 1024,  512, 1, 4, actB, 1, csumA[5], csumsqA[5], nullptr);
    run_layer(actB, B,  512,  256, 2, 5, q3,   0, nullptr,  nullptr,    nullptr);

    // fused attention
    flash_mfma<<<dim3(B / 128, NSPLIT), 256, 0, stream>>>(q3, k3, k2n, y_n, pm, pl, po,
                                                          N, N / NSPLIT, NSPLIT);
    combine_k<<<B / 256, 256, 0, stream>>>(pm, pl, po, (float*)d_out, B, NSPLIT);
}

// Round 5
// 281.363 us; speedup vs baseline: 7.5082x; 1.4855x over previous
//
#include <hip/hip_runtime.h>
#include <math.h>
#include <stdint.h>

// ---------------------------------------------------------------------------
// fp16 MFMA, R5: swizzled LDS (2-way instead of 8/16-way bank conflicts),
// BK=64 GEMM (half the barrier drains), k+q trunk layers merged into single
// dispatches, bn_prep folded into wprep, flash with register-resident Q and
// whole-chunk K staging (2 barriers/chunk, epilogue overlaps K DMA).
// ---------------------------------------------------------------------------

typedef __attribute__((ext_vector_type(8))) _Float16 half8;
typedef __attribute__((ext_vector_type(4))) _Float16 half4;
typedef __attribute__((ext_vector_type(4))) float floatx4;

__device__ __forceinline__ float fast_tanh(float x) {
    float ax = fabsf(x);
    float e  = __expf(-2.0f * ax);
    float r  = (1.0f - e) / (1.0f + e);
    return copysignf(r, x);
}
// async global->LDS, 16B per lane; LDS dest = wave-uniform base + lane*16
__device__ __forceinline__ void gload16(const void* g, void* l) {
    __builtin_amdgcn_global_load_lds(
        (__attribute__((address_space(1))) void*)(uintptr_t)(g),
        (__attribute__((address_space(3))) void*)(unsigned int)(uintptr_t)(l),
        16, 0, 0);
}

// -------- fp32 -> fp16 convert + column stats for BOTH inputs --------------
// blocks [0,256): x_n rows; [256,384): x rows. C=1024, 32 rows/block.
__global__ __launch_bounds__(256) void tof16_stats_all(
        const float* __restrict__ xn, const float* __restrict__ x,
        _Float16* __restrict__ xnh, _Float16* __restrict__ xh,
        float* __restrict__ cs0, float* __restrict__ cq0,
        float* __restrict__ cs3, float* __restrict__ cq3) {
    const float* in; _Float16* out; float *cs, *cq; int r0;
    if (blockIdx.x < 256) { in = xn; out = xnh; cs = cs0; cq = cq0; r0 = blockIdx.x * 32; }
    else                  { in = x;  out = xh;  cs = cs3; cq = cq3; r0 = (blockIdx.x - 256) * 32; }
    const int c = threadIdx.x * 4;
    float s0 = 0.f, s1 = 0.f, s2 = 0.f, s3 = 0.f;
    float q0 = 0.f, q1 = 0.f, q2 = 0.f, q3 = 0.f;
    for (int r = r0; r < r0 + 32; ++r) {
        float4 v = *(const float4*)&in[(size_t)r * 1024 + c];
        half4 h;
        h[0] = (_Float16)v.x; h[1] = (_Float16)v.y;
        h[2] = (_Float16)v.z; h[3] = (_Float16)v.w;
        *(half4*)&out[(size_t)r * 1024 + c] = h;
        s0 += v.x; q0 += v.x * v.x;
        s1 += v.y; q1 += v.y * v.y;
        s2 += v.z; q2 += v.z * v.z;
        s3 += v.w; q3 += v.w * v.w;
    }
    atomicAdd(&cs[c + 0], s0); atomicAdd(&cq[c + 0], q0);
    atomicAdd(&cs[c + 1], s1); atomicAdd(&cq[c + 1], q1);
    atomicAdd(&cs[c + 2], s2); atomicAdd(&cq[c + 2], q2);
    atomicAdd(&cs[c + 3], s3); atomicAdd(&cq[c + 3], q3);
}

// -------- wprep2: BN fold (inline) + W'T = fp16(s*W)^T + bacc = t@W --------
// z=0: k-trunk params, z=1: q-trunk params.
__global__ __launch_bounds__(256) void wprep2(
        const float* __restrict__ W, const float* __restrict__ g,
        const float* __restrict__ beta,
        const float* __restrict__ csK, const float* __restrict__ cqK, float invRK,
        _Float16* __restrict__ WTk, float* __restrict__ baccK,
        const float* __restrict__ csQ, const float* __restrict__ cqQ, float invRQ,
        _Float16* __restrict__ WTq, float* __restrict__ baccQ,
        int C, int F) {
    const int z = blockIdx.z;
    const float* cs = z ? csQ : csK;
    const float* cq = z ? cqQ : cqK;
    const float invR = z ? invRQ : invRK;
    _Float16* WT = z ? WTq : WTk;
    float* bacc = z ? baccQ : baccK;

    __shared__ float sv[32], tv[32];
    __shared__ float tile[32][33];
    __shared__ float lds2[8][32];
    const int c0 = blockIdx.y * 32, f0 = blockIdx.x * 32;
    const int tx = threadIdx.x & 31, ty = threadIdx.x >> 5;   // 32x8
    if (ty == 0) {
        int c = c0 + tx;
        float mean = cs[c] * invR;
        float var  = fmaxf(cq[c] * invR - mean * mean, 0.f);
        float s    = g[c] * rsqrtf(var + 1e-5f);
        sv[tx] = s;
        tv[tx] = beta[c] - mean * s;
    }
    __syncthreads();
    float pacc = 0.f;
#pragma unroll
    for (int i = 0; i < 32; i += 8) {
        float w = W[(size_t)(c0 + ty + i) * F + f0 + tx];
        tile[ty + i][tx] = w * sv[ty + i];
        pacc += w * tv[ty + i];
    }
    lds2[ty][tx] = pacc;
    __syncthreads();
#pragma unroll
    for (int i = 0; i < 32; i += 8)
        WT[(size_t)(f0 + ty + i) * C + c0 + tx] = (_Float16)tile[tx][ty + i];
    if (ty == 0) {
        float a = 0.f;
#pragma unroll
        for (int j = 0; j < 8; ++j) a += lds2[j][tx];
        atomicAdd(&bacc[f0 + tx], a);
    }
}

// -------- combined TN fp16 MFMA GEMM (k-trunk + q-trunk in one grid) -------
// blocks [0,64): k rows (M=8192); [64,96): q rows (M=4096). BK=64, swizzled.
// SMODE: 0 plain, 1 column stats for next BN, 2 row sumsq (||k||^2).
__global__ __launch_bounds__(256, 2) void gemm_tn_tanh(
        const _Float16* __restrict__ Ak, const _Float16* __restrict__ Aq,
        const _Float16* __restrict__ WTk, const _Float16* __restrict__ WTq,
        const float* __restrict__ bias,
        const float* __restrict__ baccK, const float* __restrict__ baccQ,
        _Float16* __restrict__ Yk, _Float16* __restrict__ Yq,
        int K, int F, int smodeK, int smodeQ,
        float* __restrict__ csK, float* __restrict__ cqK,
        float* __restrict__ csQ, float* __restrict__ cqQ,
        float* __restrict__ rowsqK) {
    __shared__ _Float16 As[128 * 64];
    __shared__ _Float16 Bs[128 * 64];
    const int tid = threadIdx.x;
    const int wv = tid >> 6, ln = tid & 63;
    const int quad = ln >> 4, l16 = ln & 15;
    const int wr = wv >> 1, wc = wv & 1;

    const bool isK = blockIdx.x < 64;
    const _Float16* A  = isK ? Ak : Aq;
    const _Float16* WT = isK ? WTk : WTq;
    const float* bacc  = isK ? baccK : baccQ;
    _Float16* Y        = isK ? Yk : Yq;
    const int smode    = isK ? smodeK : smodeQ;
    float* cs = isK ? csK : csQ;
    float* cq = isK ? cqK : cqQ;
    const int i0 = (isK ? blockIdx.x : blockIdx.x - 64) * 128;
    const int f0 = blockIdx.y * 128;

    floatx4 acc[4][4];
#pragma unroll
    for (int a = 0; a < 4; ++a)
#pragma unroll
        for (int b = 0; b < 4; ++b) acc[a][b] = (floatx4)0.f;

    for (int k0 = 0; k0 < K; k0 += 64) {
        const char* Ab = (const char*)(A + (size_t)i0 * K + k0);
        const char* Bb = (const char*)(WT + (size_t)f0 * K + k0);
        // stage 128x64 each, 8 segs/row, phys seg p holds logical (p^row)&7
#pragma unroll
        for (int it = 0; it < 4; ++it) {
            int seg = it * 256 + tid;
            int row = seg >> 3, p = seg & 7;
            int lcol = (p ^ row) & 7;
            gload16(Ab + (size_t)row * (K * 2) + lcol * 16, (char*)As + seg * 16);
        }
#pragma unroll
        for (int it = 0; it < 4; ++it) {
            int seg = it * 256 + tid;
            int row = seg >> 3, p = seg & 7;
            int lcol = (p ^ row) & 7;
            gload16(Bb + (size_t)row * (K * 2) + lcol * 16, (char*)Bs + seg * 16);
        }
        __syncthreads();
#pragma unroll
        for (int kk = 0; kk < 2; ++kk) {
            half8 af[4], bf[4];
#pragma unroll
            for (int t = 0; t < 4; ++t) {
                int ra = wr * 64 + t * 16 + l16;
                int ca = ((kk * 4 + quad) ^ ra) & 7;
                af[t] = *(const half8*)((const char*)As + ra * 128 + ca * 16);
                int rb = wc * 64 + t * 16 + l16;
                int cb = ((kk * 4 + quad) ^ rb) & 7;
                bf[t] = *(const half8*)((const char*)Bs + rb * 128 + cb * 16);
            }
#pragma unroll
            for (int tr = 0; tr < 4; ++tr)
#pragma unroll
                for (int tc = 0; tc < 4; ++tc)
                    acc[tr][tc] = __builtin_amdgcn_mfma_f32_16x16x32_f16(af[tr], bf[tc], acc[tr][tc], 0, 0, 0);
        }
        __syncthreads();
    }
    // epilogue: tanh + store; keep activations for stats
#pragma unroll
    for (int tc = 0; tc < 4; ++tc) {
        int f = f0 + wc * 64 + tc * 16 + l16;
        float bb = bias[f] + bacc[f];
#pragma unroll
        for (int tr = 0; tr < 4; ++tr)
#pragma unroll
            for (int r = 0; r < 4; ++r) {
                int row = i0 + wr * 64 + tr * 16 + quad * 4 + r;
                float v = fast_tanh(acc[tr][tc][r] + bb);
                acc[tr][tc][r] = v;
                Y[(size_t)row * F + f] = (_Float16)v;
            }
    }
    if (smode == 1) {
#pragma unroll
        for (int tc = 0; tc < 4; ++tc) {
            int f = f0 + wc * 64 + tc * 16 + l16;
            float s = 0.f, q = 0.f;
#pragma unroll
            for (int tr = 0; tr < 4; ++tr)
#pragma unroll
                for (int r = 0; r < 4; ++r) {
                    float v = acc[tr][tc][r];
                    s += v; q += v * v;
                }
            s += __shfl_xor(s, 16); q += __shfl_xor(q, 16);
            s += __shfl_xor(s, 32); q += __shfl_xor(q, 32);
            if (quad == 0) {
                atomicAdd(&cs[f], s);
                atomicAdd(&cq[f], q);
            }
        }
    } else if (smode == 2) {
#pragma unroll
        for (int tr = 0; tr < 4; ++tr)
#pragma unroll
            for (int r = 0; r < 4; ++r) {
                float rq = 0.f;
#pragma unroll
                for (int tc = 0; tc < 4; ++tc) {
                    float v = acc[tr][tc][r];
                    rq += v * v;
                }
                rq += __shfl_xor(rq, 1); rq += __shfl_xor(rq, 2);
                rq += __shfl_xor(rq, 4); rq += __shfl_xor(rq, 8);
                if (l16 == 0)
                    atomicAdd(&rowsqK[i0 + wr * 64 + tr * 16 + quad * 4 + r], rq);
            }
    }
}

// -------- flash: S = Q.K^T (K=256), logits = 2S - k2, online softmax -------
// Q fragments register-resident; K chunk (128x256) staged whole per j-iter.
__global__ __launch_bounds__(256, 2) void flash_mfma(
        const _Float16* __restrict__ Q, const _Float16* __restrict__ K3,
        const float* __restrict__ k2n, const float* __restrict__ yv,
        float* __restrict__ pm, float* __restrict__ pl, float* __restrict__ po,
        int jlen, int nsplit) {
    __shared__ _Float16 Ts[128 * 256];   // 64 KB, Q then K chunks
    const int tid = threadIdx.x;
    const int wv = tid >> 6, ln = tid & 63;
    const int quad = ln >> 4, l16 = ln & 15;
    const int i0 = blockIdx.x * 128;
    const int jb = blockIdx.y * jlen;
    const int nch = jlen >> 7;

    // stage a 128x256 fp16 tile (row stride 512B, 32 segs/row) with swizzle:
    // phys seg p of row r holds logical (p&24)|((p^r)&7)
    auto stageTile = [&](const _Float16* src, int row0) {
        const char* sb = (const char*)(src + (size_t)row0 * 256);
#pragma unroll
        for (int it = 0; it < 16; ++it) {
            int seg = it * 256 + tid;
            int row = seg >> 5, p = seg & 31;
            int lcol = (p & 24) | ((p ^ row) & 7);
            gload16(sb + (size_t)row * 512 + lcol * 16, (char*)Ts + seg * 16);
        }
    };

    // ---- Q tile -> registers ----
    stageTile(Q, i0);
    __syncthreads();
    half8 qf[2][8];
#pragma unroll
    for (int tr = 0; tr < 2; ++tr)
#pragma unroll
        for (int k0 = 0; k0 < 8; ++k0) {
            int row = wv * 32 + tr * 16 + l16;
            int c = k0 * 4 + quad;
            int phys = (c & 24) | ((c ^ row) & 7);
            qf[tr][k0] = *(const half8*)((const char*)Ts + row * 512 + phys * 16);
        }
    asm volatile("s_waitcnt lgkmcnt(0)" ::: "memory");
    __syncthreads();

    float mrun[2][4], lrun[2][4], orun[2][4];
#pragma unroll
    for (int tr = 0; tr < 2; ++tr)
#pragma unroll
        for (int r = 0; r < 4; ++r) { mrun[tr][r] = -INFINITY; lrun[tr][r] = 0.f; orun[tr][r] = 0.f; }

    stageTile(K3, jb);
    __syncthreads();
    for (int jc = 0; jc < nch; ++jc) {
        const int j0 = jb + jc * 128;
        floatx4 acc[2][8];
#pragma unroll
        for (int a = 0; a < 2; ++a)
#pragma unroll
            for (int b = 0; b < 8; ++b) acc[a][b] = (floatx4)0.f;
#pragma unroll
        for (int k0 = 0; k0 < 8; ++k0) {
            half8 kf[8];
#pragma unroll
            for (int tc = 0; tc < 8; ++tc) {
                int row = tc * 16 + l16;
                int c = k0 * 4 + quad;
                int phys = (c & 24) | ((c ^ row) & 7);
                kf[tc] = *(const half8*)((const char*)Ts + row * 512 + phys * 16);
            }
#pragma unroll
            for (int tr = 0; tr < 2; ++tr)
#pragma unroll
                for (int tc = 0; tc < 8; ++tc)
                    acc[tr][tc] = __builtin_amdgcn_mfma_f32_16x16x32_f16(qf[tr][k0], kf[tc], acc[tr][tc], 0, 0, 0);
        }
        __syncthreads();                       // all waves done reading Ts
        if (jc + 1 < nch) stageTile(K3, j0 + 128);  // async; epilogue hides it
        // ---- online softmax on this 128-col chunk ----
        float k2v[8], yv8[8];
#pragma unroll
        for (int tc = 0; tc < 8; ++tc) {
            int j = j0 + tc * 16 + l16;
            k2v[tc] = k2n[j];
            yv8[tc] = yv[j];
        }
#pragma unroll
        for (int tr = 0; tr < 2; ++tr)
#pragma unroll
            for (int r = 0; r < 4; ++r) {
                float lg[8], mt = -INFINITY;
#pragma unroll
                for (int tc = 0; tc < 8; ++tc) {
                    lg[tc] = 2.f * acc[tr][tc][r] - k2v[tc];
                    mt = fmaxf(mt, lg[tc]);
                }
#pragma unroll
                for (int m = 1; m < 16; m <<= 1) mt = fmaxf(mt, __shfl_xor(mt, m));
                float mnew = fmaxf(mrun[tr][r], mt);
                float sp = 0.f, spy = 0.f;
#pragma unroll
                for (int tc = 0; tc < 8; ++tc) {
                    float p = __expf(lg[tc] - mnew);
                    sp  += p;
                    spy += p * yv8[tc];
                }
#pragma unroll
                for (int m = 1; m < 16; m <<= 1) {
                    sp  += __shfl_xor(sp, m);
                    spy += __shfl_xor(spy, m);
                }
                float sc = __expf(mrun[tr][r] - mnew);
                lrun[tr][r] = lrun[tr][r] * sc + sp;
                orun[tr][r] = orun[tr][r] * sc + spy;
                mrun[tr][r] = mnew;
            }
        if (jc + 1 < nch) __syncthreads();     // drains K DMA before next MFMA
    }
    if (l16 == 0) {
#pragma unroll
        for (int tr = 0; tr < 2; ++tr)
#pragma unroll
            for (int r = 0; r < 4; ++r) {
                int row = i0 + wv * 32 + tr * 16 + quad * 4 + r;
                size_t idx = (size_t)row * nsplit + blockIdx.y;
                pm[idx] = mrun[tr][r];
                pl[idx] = lrun[tr][r];
                po[idx] = orun[tr][r];
            }
    }
}

// -------- combine j-split partials -----------------------------------------
__global__ void combine_k(const float* __restrict__ pm, const float* __restrict__ pl,
                          const float* __restrict__ po, float* __restrict__ out,
                          int B, int nsplit) {
    int i = blockIdx.x * blockDim.x + threadIdx.x;
    if (i >= B) return;
    float M = -INFINITY;
    for (int s = 0; s < nsplit; ++s) M = fmaxf(M, pm[(size_t)i * nsplit + s]);
    float L = 0.f, O = 0.f;
    for (int s = 0; s < nsplit; ++s) {
        float w = __expf(pm[(size_t)i * nsplit + s] - M);
        L += pl[(size_t)i * nsplit + s] * w;
        O += po[(size_t)i * nsplit + s] * w;
    }
    float r = O / L;
    out[i] = fminf(fmaxf(r, 0.f), 1.f);
}

// ---------------------------------------------------------------------------
extern "C" void kernel_launch(void* const* d_in, const int* in_sizes, int n_in,
                              void* d_out, int out_size, void* d_ws, size_t ws_size,
                              hipStream_t stream) {
    const float* x   = (const float*)d_in[0];   // [4096,1024]
    const float* x_n = (const float*)d_in[1];   // [8192,1024]
    const float* y_n = (const float*)d_in[2];   // [8192,1]
    const float* Wm[3]    = {(const float*)d_in[3],  (const float*)d_in[7],  (const float*)d_in[11]};
    const float* bm[3]    = {(const float*)d_in[4],  (const float*)d_in[8],  (const float*)d_in[12]};
    const float* gm[3]    = {(const float*)d_in[5],  (const float*)d_in[9],  (const float*)d_in[13]};
    const float* betam[3] = {(const float*)d_in[6],  (const float*)d_in[10], (const float*)d_in[14]};
    (void)in_sizes; (void)n_in; (void)out_size; (void)ws_size;

    const int B = 4096, N = 8192;
    const int NSPLIT = 16;
    const size_t M1 = 1024 * 1024;

    // ---- workspace (halfs): buffers reused across layers ----
    _Float16* h0 = (_Float16*)d_ws;        // 8M halfs: xnh  -> actBk
    _Float16* h1 = h0 + 8 * M1;            // 4M halfs: xh   -> actBq
    _Float16* h2 = h1 + 4 * M1;            // 8M halfs: actAk -> k3 | q3
    _Float16* h3 = h2 + 8 * M1;            // 4M halfs: actAq
    _Float16* WTk = h3 + 4 * M1;           // 1M halfs
    _Float16* WTq = WTk + M1;              // 1M halfs
    float* fb = (float*)(WTq + M1);
    // stat sets: 0 x_n, 1 act1k, 2 act2k, 3 x, 4 act1q, 5 act2q
    float* csA[6], *cqA[6];
    for (int i = 0; i < 6; ++i) { csA[i] = fb + i * 2048; cqA[i] = fb + i * 2048 + 1024; }
    float* baccK[3], *baccQ[3];
    for (int i = 0; i < 3; ++i) { baccK[i] = fb + 12288 + i * 1024; baccQ[i] = fb + 15360 + i * 1024; }
    float* k2n = fb + 18432;                            // 8192
    const size_t zero_floats = 18432 + 8192;            // through k2n
    float* pm = fb + zero_floats;
    float* pl = pm + (size_t)B * NSPLIT;
    float* po = pl + (size_t)B * NSPLIT;

    _Float16* xnh = h0, *xh = h1;
    _Float16* actAk = h2, *actAq = h3;
    _Float16* actBk = h0, *actBq = h1;
    _Float16* k3 = h2, *q3 = h2 + 2 * M1;

    hipMemsetAsync(fb, 0, zero_floats * sizeof(float), stream);
    tof16_stats_all<<<384, 256, 0, stream>>>(x_n, x, xnh, xh,
                                             csA[0], cqA[0], csA[3], cqA[3]);
    const float invRK = 1.0f / (float)N, invRQ = 1.0f / (float)B;

    // L1: C=1024, F=1024
    wprep2<<<dim3(1024 / 32, 1024 / 32, 2), 256, 0, stream>>>(
        Wm[0], gm[0], betam[0], csA[0], cqA[0], invRK, WTk, baccK[0],
        csA[3], cqA[3], invRQ, WTq, baccQ[0], 1024, 1024);
    gemm_tn_tanh<<<dim3(96, 1024 / 128), 256, 0, stream>>>(
        xnh, xh, WTk, WTq, bm[0], baccK[0], baccQ[0], actAk, actAq,
        1024, 1024, 1, 1, csA[1], cqA[1], csA[4], cqA[4], nullptr);
    // L2: C=1024, F=512
    wprep2<<<dim3(512 / 32, 1024 / 32, 2), 256, 0, stream>>>(
        Wm[1], gm[1], betam[1], csA[1], cqA[1], invRK, WTk, baccK[1],
        csA[4], cqA[4], invRQ, WTq, baccQ[1], 1024, 512);
    gemm_tn_tanh<<<dim3(96, 512 / 128), 256, 0, stream>>>(
        actAk, actAq, WTk, WTq, bm[1], baccK[1], baccQ[1], actBk, actBq,
        1024, 512, 1, 1, csA[2], cqA[2], csA[5], cqA[5], nullptr);
    // L3: C=512, F=256 ; k-part emits ||k||^2
    wprep2<<<dim3(256 / 32, 512 / 32, 2), 256, 0, stream>>>(
        Wm[2], gm[2], betam[2], csA[2], cqA[2], invRK, WTk, baccK[2],
        csA[5], cqA[5], invRQ, WTq, baccQ[2], 512, 256);
    gemm_tn_tanh<<<dim3(96, 256 / 128), 256, 0, stream>>>(
        actBk, actBq, WTk, WTq, bm[2], baccK[2], baccQ[2], k3, q3,
        512, 256, 2, 0, nullptr, nullptr, nullptr, nullptr, k2n);

    // attention
    flash_mfma<<<dim3(B / 128, NSPLIT), 256, 0, stream>>>(
        q3, k3, k2n, y_n, pm, pl, po, N / NSPLIT, NSPLIT);
    combine_k<<<B / 256, 256, 0, stream>>>(pm, pl, po, (float*)d_out, B, NSPLIT);
}